// Round 1
// baseline (928.158 us; speedup 1.0000x reference)
//
#include <hip/hip_runtime.h>
#include <stdint.h>

static constexpr int T_STEPS = 15;
static constexpr int C_IN = 6;
static constexpr int C_OUT = 64;
static constexpr int H = 256;
static constexpr int W = 256;
static constexpr int NPOS = H * W;            // 65536
static constexpr int NTAP = 150;              // 6*5*5
#define DTHRESH 15.0

// workspace layout (bytes); total needed = 5,767,168 (~5.5 MB)
static constexpr size_t WS_FT     = 0;                              // uint8 [C_IN*NPOS]
static constexpr size_t WS_SERIES = 393216;                         // float [NPOS*16]
static constexpr size_t WS_WINC   = WS_SERIES + (size_t)NPOS*16*4;  // int8  [NPOS]
static constexpr size_t WS_NMAP   = WS_WINC + (size_t)NPOS;         // uint8 [NPOS]
static constexpr size_t WS_VAL    = WS_NMAP + (size_t)NPOS;         // double[NPOS]
static constexpr size_t WS_TOTAL  = WS_VAL + (size_t)NPOS*8;        // double[NPOS]
static constexpr size_t WS_NEED   = WS_TOTAL + (size_t)NPOS*8;

// ---------------- K1: first-spike-time map ----------------
__global__ __launch_bounds__(256) void ft_kernel(const float* __restrict__ x,
                                                 uint8_t* __restrict__ ft) {
    int i = blockIdx.x * 256 + threadIdx.x;
    if (i >= C_IN * NPOS) return;
    int f = 15;
    #pragma unroll
    for (int t = T_STEPS - 1; t >= 0; --t) {
        if (x[(size_t)t * (C_IN * NPOS) + i] > 0.0f) f = t;
    }
    ft[i] = (uint8_t)f;
}

// ---------------- K2: per-position conv-as-sorted-accumulate + pointwise WTA ----------------
// One wave per (h,w); lane = output channel. Block = 4 waves handles 16 consecutive w.
__global__ __launch_bounds__(256) void conv_kernel(
        const float* __restrict__ w1, const uint8_t* __restrict__ ftg,
        float* __restrict__ series_ws, int8_t* __restrict__ winc_ws,
        uint8_t* __restrict__ nmap_ws, double* __restrict__ val_ws)
{
    __shared__ float w_lds[NTAP * 64];           // [tap][o], stride-1 across lanes
    __shared__ uint8_t ft_lds[6 * 5 * 24];       // [c][kh][col 0..19], pad to 24
    __shared__ unsigned cnt_lds[4][16];
    __shared__ unsigned short sorted_lds[4][160];

    int tid = threadIdx.x;
    int bid = blockIdx.x;                        // 0..4095
    int h  = bid >> 4;
    int w0 = (bid & 15) << 4;

    // stage weights transposed: w_lds[tap*64 + o] = w1[o*150 + tap]
    for (int i = tid; i < C_OUT * NTAP; i += 256) {
        int o = i / NTAP;
        int tap = i - o * NTAP;
        w_lds[tap * 64 + o] = w1[i];
    }
    // stage ft tile with pad-of-15 (never spikes) outside the image
    for (int i = tid; i < 600; i += 256) {
        int c = i / 100;
        int r = i - c * 100;
        int kh = r / 20;
        int j  = r - kh * 20;
        int gh = h - 2 + kh;
        int gw = w0 - 2 + j;
        uint8_t v = 15;
        if (gh >= 0 && gh < H && gw >= 0 && gw < W) v = ftg[c * NPOS + gh * W + gw];
        ft_lds[(c * 5 + kh) * 24 + j] = v;
    }
    __syncthreads();

    int lane = tid & 63;
    int wv   = tid >> 6;

    for (int iter = 0; iter < 4; ++iter) {
        int xl = iter * 4 + wv;                  // local col 0..15
        int p  = h * W + w0 + xl;

        if (lane < 16) cnt_lds[wv][lane] = 0;
        __syncthreads();

        // counting sort of the 150 taps by first-spike time (3 tap slots per lane)
        int tap0 = lane, tap1 = lane + 64, tap2 = lane + 128;
        auto ftv = [&](int tap) -> unsigned {
            int c = tap / 25;
            int r = tap - c * 25;
            int kh = r / 5;
            int kw = r - kh * 5;
            return ft_lds[(c * 5 + kh) * 24 + xl + kw];
        };
        unsigned f0 = ftv(tap0);
        unsigned f1 = ftv(tap1);
        unsigned f2 = (tap2 < NTAP) ? ftv(tap2) : 15u;
        unsigned r0 = 0, r1 = 0, r2 = 0;
        if (f0 < 15u) r0 = atomicAdd(&cnt_lds[wv][f0], 1u);
        if (f1 < 15u) r1 = atomicAdd(&cnt_lds[wv][f1], 1u);
        if (f2 < 15u) r2 = atomicAdd(&cnt_lds[wv][f2], 1u);
        __syncthreads();

        unsigned st0 = 0, st1 = 0, st2 = 0;
        #pragma unroll
        for (int t = 0; t < 15; ++t) {
            unsigned cv = cnt_lds[wv][t];
            if ((unsigned)t < f0) st0 += cv;
            if ((unsigned)t < f1) st1 += cv;
            if ((unsigned)t < f2) st2 += cv;
        }
        if (f0 < 15u) sorted_lds[wv][st0 + r0] = (unsigned short)(tap0 << 6);
        if (f1 < 15u) sorted_lds[wv][st1 + r1] = (unsigned short)(tap1 << 6);
        if (f2 < 15u) sorted_lds[wv][st2 + r2] = (unsigned short)(tap2 << 6);
        __syncthreads();

        // main accumulate: running fp64 potential per channel, t-ordered
        double run = 0.0;
        double series[15];
        int e = -1, wc = -1;
        double val = 0.0;
        int j = 0;
        #pragma unroll
        for (int t = 0; t < 15; ++t) {
            int k = (int)__builtin_amdgcn_readfirstlane(cnt_lds[wv][t]);
            for (int q = 0; q < k; ++q) {
                int woff = sorted_lds[wv][j + q];        // broadcast read
                run += (double)w_lds[woff + lane];       // stride-1 read
            }
            j += k;
            series[t] = run;
            if (e < 0) {
                unsigned long long b = __ballot(run >= DTHRESH);
                if (b != 0ull) {                         // uniform branch
                    e = t;
                    double vl = (run >= DTHRESH) ? run : 0.0;
                    double m = vl;
                    #pragma unroll
                    for (int off = 32; off >= 1; off >>= 1)
                        m = fmax(m, __shfl_xor(m, off));
                    unsigned long long mk = __ballot(vl == m);
                    wc = __ffsll(mk) - 1;                // first-index tie-break
                    val = m;
                }
            }
        }

        if (wc >= 0) {
            float outv = 0.0f;
            #pragma unroll
            for (int t = 0; t < 15; ++t) {
                double sv = __shfl(series[t], wc);
                if (lane == t) outv = (sv >= DTHRESH) ? (float)sv : 0.0f;
            }
            if (lane < 15) series_ws[p * 16 + lane] = outv;
        }
        if (lane == 0) {
            winc_ws[p] = (int8_t)wc;
            nmap_ws[p] = (uint8_t)(wc >= 0 ? (15 - e) : 0);
            if (wc >= 0) val_ws[p] = val;
        }
    }
}

// ---------------- K3: sequential 5-round k-winners (single block) ----------------
__global__ __launch_bounds__(1024) void kwin_kernel(
        const int8_t* __restrict__ winc, const uint8_t* __restrict__ nmap,
        const double* __restrict__ val, double* __restrict__ total,
        float* __restrict__ outw)
{
    __shared__ double redv[1024];
    __shared__ unsigned redi[1024];
    __shared__ int bc_c, bc_h, bc_w;
    int tid = threadIdx.x;

    // v = T * max(val over winners)
    double mv = 0.0;
    for (int k = 0; k < 64; ++k) {
        int p = tid + (k << 10);
        if (winc[p] >= 0) mv = fmax(mv, val[p]);
    }
    redv[tid] = mv;
    __syncthreads();
    for (int s = 512; s > 0; s >>= 1) {
        if (tid < s) redv[tid] = fmax(redv[tid], redv[tid + s]);
        __syncthreads();
    }
    double v = 15.0 * redv[0];
    __syncthreads();

    for (int k = 0; k < 64; ++k) {
        int p = tid + (k << 10);
        int c = winc[p];
        total[p] = (c >= 0) ? (double)nmap[p] * (val[p] + v) : 0.0;
    }
    __threadfence_block();
    __syncthreads();

    for (int r = 0; r < 5; ++r) {
        double bv = -1.0;
        unsigned bi = 0xFFFFFFFFu;
        for (int k = 0; k < 64; ++k) {
            int p = tid + (k << 10);
            double tv = total[p];
            int c = winc[p];
            unsigned cc = (c >= 0) ? (unsigned)c : 0u;
            unsigned fi = (cc << 16) | (unsigned)p;      // c-major flat index (argmax order)
            if (tv > bv || (tv == bv && fi < bi)) { bv = tv; bi = fi; }
        }
        redv[tid] = bv; redi[tid] = bi;
        __syncthreads();
        for (int s = 512; s > 0; s >>= 1) {
            if (tid < s) {
                double ov = redv[tid + s]; unsigned oi = redi[tid + s];
                if (ov > redv[tid] || (ov == redv[tid] && oi < redi[tid])) {
                    redv[tid] = ov; redi[tid] = oi;
                }
            }
            __syncthreads();
        }
        if (tid == 0) {
            double wvv = redv[0];
            unsigned wi = redi[0];
            int c  = (int)(wi >> 16);
            int pp = (int)(wi & 0xFFFFu);
            int hh = pp >> 8, ww = pp & 255;
            bool valid = (wvv != 0.0);
            outw[r * 3 + 0] = valid ? (float)c  : -1.0f;
            outw[r * 3 + 1] = valid ? (float)hh : -1.0f;
            outw[r * 3 + 2] = valid ? (float)ww : -1.0f;
            bc_c = c; bc_h = hh; bc_w = ww;
        }
        __syncthreads();
        int cw = bc_c, hw2 = bc_h, ww2 = bc_w;
        for (int k = 0; k < 64; ++k) {
            int p = tid + (k << 10);
            int hh = p >> 8, wcol = p & 255;
            bool kill = ((int)winc[p] == cw) ||
                        (hh >= hw2 - 3 && hh <= hw2 + 3 &&
                         wcol >= ww2 - 3 && wcol <= ww2 + 3);
            if (kill) total[p] = 0.0;
        }
        __threadfence_block();
        __syncthreads();
    }
}

// ---------------- K4: expand winner map to full spk/pot outputs (coalesced float4) ----------------
__global__ __launch_bounds__(256) void expand_kernel(
        const int8_t* __restrict__ winc, const float* __restrict__ series,
        float* __restrict__ spk, float* __restrict__ pot)
{
    int idx4 = blockIdx.x * 256 + threadIdx.x;   // < 15,728,640
    int w4 = idx4 & 63;
    int h  = (idx4 >> 6) & 255;
    int c  = (idx4 >> 14) & 63;
    int t  = idx4 >> 20;
    int pbase = h * W + (w4 << 2);
    uint32_t wcs = *reinterpret_cast<const uint32_t*>(winc + pbase);
    float4 pv = make_float4(0.f, 0.f, 0.f, 0.f);
    float4 sv = make_float4(0.f, 0.f, 0.f, 0.f);
    #pragma unroll
    for (int e2 = 0; e2 < 4; ++e2) {
        int8_t wcb = (int8_t)((wcs >> (8 * e2)) & 0xFFu);
        if ((int)wcb == c) {
            float xv = series[(size_t)(pbase + e2) * 16 + t];
            (&pv.x)[e2] = xv;
            (&sv.x)[e2] = (xv > 0.f) ? 1.0f : 0.0f;
        }
    }
    reinterpret_cast<float4*>(spk)[idx4] = sv;
    reinterpret_cast<float4*>(pot)[idx4] = pv;
}

extern "C" void kernel_launch(void* const* d_in, const int* in_sizes, int n_in,
                              void* d_out, int out_size, void* d_ws, size_t ws_size,
                              hipStream_t stream)
{
    if (ws_size < WS_NEED) return;   // needs ~5.5 MB scratch

    const float* x  = (const float*)d_in[0];
    const float* w1 = (const float*)d_in[1];
    uint8_t* ws = (uint8_t*)d_ws;
    uint8_t* ftg    = ws + WS_FT;
    float*   series = (float*)(ws + WS_SERIES);
    int8_t*  winc   = (int8_t*)(ws + WS_WINC);
    uint8_t* nmap   = (uint8_t*)(ws + WS_NMAP);
    double*  val    = (double*)(ws + WS_VAL);
    double*  total  = (double*)(ws + WS_TOTAL);

    float* spk  = (float*)d_out;
    float* pot  = spk + (size_t)T_STEPS * C_OUT * NPOS;
    float* outw = pot + (size_t)T_STEPS * C_OUT * NPOS;

    hipLaunchKernelGGL(ft_kernel,     dim3(1536),  dim3(256),  0, stream, x, ftg);
    hipLaunchKernelGGL(conv_kernel,   dim3(4096),  dim3(256),  0, stream, w1, ftg, series, winc, nmap, val);
    hipLaunchKernelGGL(kwin_kernel,   dim3(1),     dim3(1024), 0, stream, winc, nmap, val, total, outw);
    hipLaunchKernelGGL(expand_kernel, dim3(61440), dim3(256),  0, stream, winc, series, spk, pot);
}